// Round 1
// baseline (254.326 us; speedup 1.0000x reference)
//
#include <hip/hip_runtime.h>
#include <hip/hip_bf16.h>
#include <stdint.h>
#include <stddef.h>

#define DIM 768

typedef short short8 __attribute__((ext_vector_type(8)));
typedef float f32x4 __attribute__((ext_vector_type(4)));

__device__ inline unsigned short f2bf_rne(float f) {
    union { float f; unsigned u; } x; x.f = f;
    unsigned r = x.u + 0x7fffu + ((x.u >> 16) & 1u);
    return (unsigned short)(r >> 16);
}

__device__ inline void gload_lds16(const void* g, void* l) {
    __builtin_amdgcn_global_load_lds((const __attribute__((address_space(1))) void*)g,
                                     (__attribute__((address_space(3))) void*)l, 16, 0, 0);
}

// Kernel 1: gather embedding rows; bf16 copy -> ws A; fp32 passthrough for need==0; flags per row.
__global__ __launch_bounds__(256) void emb_gather_kernel(
    const int* __restrict__ token,
    const int* __restrict__ need_mapper,
    const float* __restrict__ emb,
    float* __restrict__ out,
    unsigned short* __restrict__ Abf,
    int* __restrict__ flags,
    int ntok)
{
    int idx = blockIdx.x * 256 + threadIdx.x;
    int trow = idx / 192;                 // 192 float4 per 768-wide row
    if (trow >= ntok) return;
    int d4 = idx - trow * 192;
    int tok = token[trow];
    int need = need_mapper[tok];
    const float4* src = (const float4*)(emb + (size_t)tok * DIM) + d4;
    float4 v = *src;
    ushort4 h;
    h.x = f2bf_rne(v.x); h.y = f2bf_rne(v.y);
    h.z = f2bf_rne(v.z); h.w = f2bf_rne(v.w);
    *((ushort4*)(Abf + (size_t)trow * DIM) + d4) = h;
    if (!need) {
        *((float4*)(out + (size_t)trow * DIM) + d4) = v;
    }
    if (d4 == 0) flags[trow] = need;
}

// Kernel 2: W [K][N] fp32 -> Wt [N][K] bf16 (transposed so GEMM B staging == A staging pattern)
__global__ __launch_bounds__(256) void convw_kernel(
    const float* __restrict__ w, unsigned short* __restrict__ Bt)
{
    int idx = blockIdx.x * 256 + threadIdx.x;
    if (idx >= DIM * DIM) return;
    int k = idx / DIM;
    int n = idx - k * DIM;
    Bt[(size_t)n * DIM + k] = f2bf_rne(w[idx]);
}

// Kernel 3: C[m][n] = sum_k A[m][k] * Bt[n][k] + bias[n], written only where flags[m]!=0.
// 128x128 tile, BK=32, 4 waves, 4x4 16x16x32 bf16 MFMA per wave (m97 structure).
__global__ __launch_bounds__(256) void gemm_map_kernel(
    const unsigned short* __restrict__ A,    // [M][768] bf16
    const unsigned short* __restrict__ Bt,   // [768][768] bf16, n-major
    const float* __restrict__ bias,          // [768] fp32
    const int* __restrict__ flags,           // [M]
    float* __restrict__ out)                 // [M][768] fp32
{
    __shared__ unsigned short As[128 * 32];
    __shared__ unsigned short Bs[128 * 32];

    const int tid  = threadIdx.x;
    const int wave = tid >> 6;
    const int lane = tid & 63;
    const int quad = lane >> 4;
    const int l15  = lane & 15;
    const int wm   = wave >> 1;          // 0..1
    const int wn   = wave & 1;           // 0..1
    const int tile_m = blockIdx.x;
    const int tile_n = blockIdx.y;

    const int srow = tid >> 2;           // 0..63 (staging row, issue j adds 64)
    const int scol = (tid & 3) * 8;      // staging col group (8 bf16 = 16 B)

    const unsigned short* Ag = A  + (size_t)(tile_m * 128 + srow) * DIM + scol;
    const unsigned short* Bg = Bt + (size_t)(tile_n * 128 + srow) * DIM + scol;

    unsigned short* AsW = As + wave * 512;    // wave-uniform LDS base (ushort units)
    unsigned short* BsW = Bs + wave * 512;

    f32x4 acc[4][4] = {};

    for (int kk = 0; kk < DIM; kk += 32) {
        __syncthreads();
        gload_lds16(Ag + kk,            AsW);
        gload_lds16(Ag + kk + 64 * DIM, AsW + 2048);
        gload_lds16(Bg + kk,            BsW);
        gload_lds16(Bg + kk + 64 * DIM, BsW + 2048);
        __syncthreads();

        short8 af[4], bf[4];
#pragma unroll
        for (int i = 0; i < 4; ++i)
            af[i] = *(const short8*)(As + (wm * 64 + i * 16 + l15) * 32 + quad * 8);
#pragma unroll
        for (int j = 0; j < 4; ++j)
            bf[j] = *(const short8*)(Bs + (wn * 64 + j * 16 + l15) * 32 + quad * 8);
#pragma unroll
        for (int i = 0; i < 4; ++i)
#pragma unroll
            for (int j = 0; j < 4; ++j)
                acc[i][j] = __builtin_amdgcn_mfma_f32_16x16x32_bf16(af[i], bf[j], acc[i][j], 0, 0, 0);
    }

    // Epilogue: C/D layout col=lane&15, row=quad*4+reg
    const int colg = tile_n * 128 + wn * 64 + l15;
    float bv[4];
#pragma unroll
    for (int j = 0; j < 4; ++j) bv[j] = bias[colg + j * 16];

    const int row0 = tile_m * 128 + wm * 64 + quad * 4;
#pragma unroll
    for (int i = 0; i < 4; ++i) {
#pragma unroll
        for (int r = 0; r < 4; ++r) {
            int gm = row0 + i * 16 + r;
            if (flags[gm] != 0) {
                float* orow = out + (size_t)gm * DIM + colg;
#pragma unroll
                for (int j = 0; j < 4; ++j)
                    orow[j * 16] = acc[i][j][r] + bv[j];
            }
        }
    }
}

extern "C" void kernel_launch(void* const* d_in, const int* in_sizes, int n_in,
                              void* d_out, int out_size, void* d_ws, size_t ws_size,
                              hipStream_t stream)
{
    const int*   token       = (const int*)d_in[0];
    const int*   need_mapper = (const int*)d_in[1];
    const float* emb         = (const float*)d_in[2];
    const float* w           = (const float*)d_in[3];
    const float* bias        = (const float*)d_in[4];
    float* out = (float*)d_out;

    const int ntok = in_sizes[0];   // 32*512 = 16384

    unsigned short* Abf = (unsigned short*)d_ws;
    unsigned short* Bt  = (unsigned short*)((char*)d_ws + (size_t)ntok * DIM * 2);
    int* flags          = (int*)((char*)d_ws + (size_t)ntok * DIM * 2 + (size_t)DIM * DIM * 2);

    int gthreads = ntok * (DIM / 4);
    emb_gather_kernel<<<dim3((gthreads + 255) / 256), dim3(256), 0, stream>>>(
        token, need_mapper, emb, out, Abf, flags, ntok);
    convw_kernel<<<dim3((DIM * DIM + 255) / 256), dim3(256), 0, stream>>>(w, Bt);
    dim3 grid(ntok / 128, DIM / 128);
    gemm_map_kernel<<<grid, dim3(256), 0, stream>>>(Abf, Bt, bias, flags, out);
}

// Round 2
// 242.805 us; speedup vs baseline: 1.0475x; 1.0475x over previous
//
#include <hip/hip_runtime.h>
#include <hip/hip_bf16.h>
#include <stdint.h>
#include <stddef.h>

#define DIM 768

typedef short short8 __attribute__((ext_vector_type(8)));
typedef float f32x4 __attribute__((ext_vector_type(4)));

__device__ inline unsigned short f2bf_rne(float f) {
    union { float f; unsigned u; } x; x.f = f;
    unsigned r = x.u + 0x7fffu + ((x.u >> 16) & 1u);
    return (unsigned short)(r >> 16);
}

__device__ inline void gload_lds16(const void* g, void* l) {
    __builtin_amdgcn_global_load_lds((const __attribute__((address_space(1))) void*)g,
                                     (__attribute__((address_space(3))) void*)l, 16, 0, 0);
}

// Kernel 1: W [K][N] fp32 -> Bt [N][K] bf16 via LDS transpose (coalesced read AND write).
__global__ __launch_bounds__(256) void convw_kernel(
    const float* __restrict__ w, unsigned short* __restrict__ Bt)
{
    __shared__ unsigned short t[64][65];
    const int k0 = blockIdx.x * 64, n0 = blockIdx.y * 64;
    const int tid = threadIdx.x;
#pragma unroll
    for (int p = 0; p < 16; ++p) {
        int e = p * 256 + tid;
        int r = e >> 6, c = e & 63;              // r: k-row, c: n-col
        t[c][r] = f2bf_rne(w[(size_t)(k0 + r) * DIM + n0 + c]);
    }
    __syncthreads();
#pragma unroll
    for (int p = 0; p < 16; ++p) {
        int e = p * 256 + tid;
        int r = e >> 6, c = e & 63;              // r: n-row, c: k-col
        Bt[(size_t)(n0 + r) * DIM + k0 + c] = t[r][c];
    }
}

// Kernel 2: fused gather + GEMM + conditional select.
// Block = 128 m-rows x 128 n-cols, BK=32, 4 waves, 4x4 16x16x32 bf16 MFMA per wave.
// A is gathered fp32 directly from the embedding table into LDS (XOR-swizzled chunk
// slots to kill the 128B-stride bank conflict), converted to bf16 in-register.
// need==0 rows are written from an L2-warm re-read of the embedding row in the epilogue.
__global__ __launch_bounds__(256) void fused_gemm_kernel(
    const int* __restrict__ token,
    const int* __restrict__ need_mapper,
    const float* __restrict__ emb,
    const unsigned short* __restrict__ Bt,   // [768][768] bf16, n-major
    const float* __restrict__ bias,
    float* __restrict__ out)                 // [M][768] fp32
{
    __shared__ float As[128 * 32];            // 16 KB, chunk-swizzled
    __shared__ unsigned short Bs[128 * 32];   // 8 KB
    __shared__ int tok_s[128];
    __shared__ int flag_s[128];

    const int tid  = threadIdx.x;
    const int wave = tid >> 6;
    const int lane = tid & 63;
    const int quad = lane >> 4;
    const int l15  = lane & 15;
    const int wm   = wave >> 1;
    const int wn   = wave & 1;
    const int tile_m = blockIdx.x;
    const int tile_n = blockIdx.y;

    if (tid < 128) {
        int t = token[tile_m * 128 + tid];
        tok_s[tid]  = t;
        flag_s[tid] = need_mapper[t];
    }
    __syncthreads();

    // A staging: issue j covers rows j*32..j*32+31; lane l -> row +(l>>3), chunk slot l&7.
    // Slot s of row r holds source chunk (s ^ (r&7))  [XOR swizzle].
    const int r8 = tid >> 3;
    const int c8 = tid & 7;
    const float* pA[4];
#pragma unroll
    for (int j = 0; j < 4; ++j) {
        int r = j * 32 + r8;
        pA[j] = emb + (size_t)tok_s[r] * DIM + ((c8 ^ (r & 7)) << 2);
    }
    float* lA0 = As + (wave * 8) * 32;        // wave-uniform LDS bases
    // B staging: row = tid>>2 (+64 on 2nd issue), 8-ushort chunk = (tid&3)*8.
    const unsigned short* pB = Bt + (size_t)(tile_n * 128 + (tid >> 2)) * DIM + (tid & 3) * 8;
    unsigned short* lB = Bs + wave * 512;

    f32x4 acc[4][4] = {};

    for (int kk = 0; kk < DIM; kk += 32) {
        __syncthreads();
#pragma unroll
        for (int j = 0; j < 4; ++j)
            gload_lds16(pA[j] + kk, lA0 + j * 32 * 32);
        gload_lds16(pB + kk,                   lB);
        gload_lds16(pB + kk + (size_t)64 * DIM, lB + 2048);
        __syncthreads();

        short8 af[4], bf[4];
#pragma unroll
        for (int i = 0; i < 4; ++i) {
            const int m = wm * 64 + i * 16 + l15;
            const float* row = As + (m << 5);
            f32x4 a0 = *(const f32x4*)(row + ((((quad << 1)    ) ^ (m & 7)) << 2));
            f32x4 a1 = *(const f32x4*)(row + ((((quad << 1) + 1) ^ (m & 7)) << 2));
            unsigned u0 = __float_as_uint(a0[0]) + 0x8000u;
            unsigned u1 = __float_as_uint(a0[1]) + 0x8000u;
            unsigned u2 = __float_as_uint(a0[2]) + 0x8000u;
            unsigned u3 = __float_as_uint(a0[3]) + 0x8000u;
            unsigned u4 = __float_as_uint(a1[0]) + 0x8000u;
            unsigned u5 = __float_as_uint(a1[1]) + 0x8000u;
            unsigned u6 = __float_as_uint(a1[2]) + 0x8000u;
            unsigned u7 = __float_as_uint(a1[3]) + 0x8000u;
            union { int i4[4]; short8 s; } pk;
            pk.i4[0] = __builtin_amdgcn_perm(u1, u0, 0x07060302);
            pk.i4[1] = __builtin_amdgcn_perm(u3, u2, 0x07060302);
            pk.i4[2] = __builtin_amdgcn_perm(u5, u4, 0x07060302);
            pk.i4[3] = __builtin_amdgcn_perm(u7, u6, 0x07060302);
            af[i] = pk.s;
        }
#pragma unroll
        for (int j = 0; j < 4; ++j)
            bf[j] = *(const short8*)(Bs + (wn * 64 + j * 16 + l15) * 32 + quad * 8);
#pragma unroll
        for (int i = 0; i < 4; ++i)
#pragma unroll
            for (int j = 0; j < 4; ++j)
                acc[i][j] = __builtin_amdgcn_mfma_f32_16x16x32_bf16(af[i], bf[j], acc[i][j], 0, 0, 0);
    }

    // Epilogue. C/D layout: col = lane&15, row = quad*4 + reg.
    const int colg = tile_n * 128 + wn * 64 + l15;
    float bv[4];
#pragma unroll
    for (int j = 0; j < 4; ++j) bv[j] = bias[colg + j * 16];

#pragma unroll
    for (int i = 0; i < 4; ++i) {
#pragma unroll
        for (int r = 0; r < 4; ++r) {
            const int lrow = wm * 64 + i * 16 + quad * 4 + r;
            const int gm   = tile_m * 128 + lrow;
            float* orow = out + (size_t)gm * DIM + colg;
            if (flag_s[lrow]) {
#pragma unroll
                for (int j = 0; j < 4; ++j)
                    orow[j * 16] = acc[i][j][r] + bv[j];
            } else {
                const float* erow = emb + (size_t)tok_s[lrow] * DIM + colg;
#pragma unroll
                for (int j = 0; j < 4; ++j)
                    orow[j * 16] = erow[j * 16];
            }
        }
    }
}

extern "C" void kernel_launch(void* const* d_in, const int* in_sizes, int n_in,
                              void* d_out, int out_size, void* d_ws, size_t ws_size,
                              hipStream_t stream)
{
    const int*   token       = (const int*)d_in[0];
    const int*   need_mapper = (const int*)d_in[1];
    const float* emb         = (const float*)d_in[2];
    const float* w           = (const float*)d_in[3];
    const float* bias        = (const float*)d_in[4];
    float* out = (float*)d_out;

    const int ntok = in_sizes[0];   // 32*512 = 16384

    unsigned short* Bt = (unsigned short*)d_ws;   // 768*768 bf16 = 1.18 MB

    convw_kernel<<<dim3(DIM / 64, DIM / 64), dim3(256), 0, stream>>>(w, Bt);
    fused_gemm_kernel<<<dim3(ntok / 128, DIM / 128), dim3(256), 0, stream>>>(
        token, need_mapper, emb, Bt, bias, out);
}